// Round 3
// baseline (752.648 us; speedup 1.0000x reference)
//
#include <hip/hip_runtime.h>
#include <hip/hip_bf16.h>

#define D 768
#define NQ 64
#define NT 64           // corpus rows per tile
#define KC 128          // fp32 cols per chunk
#define NCHT 6          // chunks per tile (768/128)
#define TPB 512
#define NBUF 4
#define SIMST 65
#define NS 8            // merge1 segments per query
#define GRID 256

#define LDS_BUF_F   (NT * KC)            // 8192 floats per buffer
#define LDS_SIM_F   (NBUF * LDS_BUF_F)   // 32768: sim region starts here
#define LDS_CN_F    (LDS_SIM_F + NQ * SIMST)
#define LDS_BYTES   ((LDS_CN_F + NT) * 4)  // 147968 B

typedef float    f32x4 __attribute__((ext_vector_type(4)));
typedef _Float16 h16x8 __attribute__((ext_vector_type(8)));

typedef const void __attribute__((address_space(1)))* gas_ptr;
typedef void __attribute__((address_space(3)))* las_ptr;

// ---------- top-k helpers (static-indexed: stays in VGPRs) ----------
__device__ __forceinline__ bool kbetter(float v1, int i1, float v2, int i2) {
    return (v1 > v2) || (v1 == v2 && i1 < i2);
}

__device__ __forceinline__ void topk_insert(float (&tv)[16], int (&ti)[16], float v, int idx) {
    if (!kbetter(v, idx, tv[15], ti[15])) return;
    tv[15] = v; ti[15] = idx;
    #pragma unroll
    for (int s = 15; s >= 1; --s) {
        bool sw = kbetter(tv[s], ti[s], tv[s-1], ti[s-1]);
        float av = sw ? tv[s] : tv[s-1];
        float bv = sw ? tv[s-1] : tv[s];
        int   ai = sw ? ti[s] : ti[s-1];
        int   bi = sw ? ti[s-1] : ti[s];
        tv[s-1] = av; tv[s] = bv; ti[s-1] = ai; ti[s] = bi;
    }
}

__device__ __forceinline__ void bitonic16(float (&v)[16], int (&ix)[16]) {
    #pragma unroll
    for (int d = 8; d >= 1; d >>= 1) {
        #pragma unroll
        for (int i = 0; i < 16; ++i) {
            if ((i & d) == 0) {
                int j = i | d;
                bool sw = kbetter(v[j], ix[j], v[i], ix[i]);
                float av = sw ? v[j] : v[i];
                float bv = sw ? v[i] : v[j];
                int   ai = sw ? ix[j] : ix[i];
                int   bi = sw ? ix[i] : ix[j];
                v[i] = av; v[j] = bv; ix[i] = ai; ix[j] = bi;
            }
        }
    }
}

__device__ __forceinline__ void lane_merge(float (&v)[16], int (&ix)[16], int mask) {
    float pv[16]; int pix[16];
    #pragma unroll
    for (int i = 0; i < 16; ++i) {
        pv[i]  = __shfl_xor(v[15 - i], mask);
        pix[i] = __shfl_xor(ix[15 - i], mask);
    }
    #pragma unroll
    for (int i = 0; i < 16; ++i) {
        if (kbetter(pv[i], pix[i], v[i], ix[i])) { v[i] = pv[i]; ix[i] = pix[i]; }
    }
    bitonic16(v, ix);
}

__device__ __forceinline__ void sort64(float& v, int& ix, int l) {
    #pragma unroll
    for (int k = 2; k <= 64; k <<= 1) {
        #pragma unroll
        for (int j = k >> 1; j >= 1; j >>= 1) {
            float ov = __shfl_xor(v, j);
            int   oi = __shfl_xor(ix, j);
            bool dirDesc = ((l & k) == 0);
            bool lower   = ((l & j) == 0);
            bool takeBetter = (lower == dirDesc);
            bool ob = kbetter(ov, oi, v, ix);
            if (takeBetter == ob) { v = ov; ix = oi; }
        }
    }
}

// ---------- kernel 0: normalize Q rows, fp16 hi/lo split, fragment order ----------
// layout: [cm(6)][ks(4)][qf(4)][lane(64)][8 halves]
__global__ __launch_bounds__(256)
void prep_kernel(const float* __restrict__ query, _Float16* __restrict__ qfh,
                 _Float16* __restrict__ qfl) {
    int b = blockIdx.x, t = threadIdx.x;
    const float* row = query + b * D;
    float vals[3]; float s = 0.f;
    #pragma unroll
    for (int j = 0; j < 3; ++j) { vals[j] = row[t + 256 * j]; s += vals[j] * vals[j]; }
    #pragma unroll
    for (int m = 1; m < 64; m <<= 1) s += __shfl_xor(s, m);
    __shared__ float ws4[4];
    if ((t & 63) == 0) ws4[t >> 6] = s;
    __syncthreads();
    float qn = sqrtf(ws4[0] + ws4[1] + ws4[2] + ws4[3]);
    int qf = b >> 4;
    #pragma unroll
    for (int j = 0; j < 3; ++j) {
        int col = t + 256 * j;
        float vn = vals[j] / qn;
        _Float16 h = (_Float16)vn;
        float r = vn - (float)h;
        _Float16 l2 = (_Float16)(r * 2048.0f);
        int cm = col >> 7, ks = (col >> 5) & 3, unit = (col >> 3) & 3, sub = col & 7;
        int lane = (b & 15) + unit * 16;
        size_t off = ((((size_t)cm * 4 + ks) * 4 + qf) * 64 + lane) * 8 + sub;
        qfh[off] = h;
        qfl[off] = l2;
    }
}

struct QF { h16x8 h[2][4]; h16x8 l[2][4]; };

// ---------- kernel 1: persistent depth-2 pipelined sim + per-tile top-16 ----------
__global__ __launch_bounds__(TPB, 2)
void sim_topk_kernel(const float* __restrict__ corpus,
                     const _Float16* __restrict__ qfh,
                     const _Float16* __restrict__ qfl,
                     float2* __restrict__ cand,   // [NQ][NTILES][16]
                     int N, int NTILES) {
    extern __shared__ __align__(16) float lds[];
    float* simF = lds + LDS_SIM_F;
    float* cnF  = lds + LDS_CN_F;

    int t = threadIdx.x, w = t >> 6, l = t & 63;
    int qfp = w >> 2, nfl = w & 3;
    int b = blockIdx.x;
    int q0 = NTILES / GRID, R = NTILES % GRID;
    int tstart = b * q0 + min(b, R);
    int cnt = q0 + (b < R ? 1 : 0);
    int NC = cnt * NCHT;

    f32x4 accH[2], accX[2];
    #pragma unroll
    for (int j = 0; j < 2; ++j) { accH[j] = (f32x4)(0.f); accX[j] = (f32x4)(0.f); }
    float psum = 0.f;

    QF qA, qB;

    auto QLOAD = [&](int cmq, QF& qd) {
        #pragma unroll
        for (int ks = 0; ks < 4; ++ks)
            #pragma unroll
            for (int j = 0; j < 2; ++j) {
                size_t off = ((((size_t)cmq * 4 + ks) * 4 + (qfp * 2 + j)) * 64 + l) * 8;
                qd.h[j][ks] = *(const h16x8*)(qfh + off);
                qd.l[j][ks] = *(const h16x8*)(qfl + off);
            }
    };

    auto STAGE = [&](int k) {
        int tile = tstart + k / NCHT;
        int cm = k % NCHT;
        float* dbase = lds + (k & 3) * LDS_BUF_F;
        #pragma unroll
        for (int jj = 0; jj < 4; ++jj) {
            int U = t + TPB * jj;
            int row = U >> 5, g = U & 31;
            int grow = tile * NT + row;
            if (grow > N - 1) grow = N - 1;
            int gs = g ^ (row & 7);
            const float* src = corpus + (size_t)grow * D + cm * KC + gs * 4;
            float* dst = dbase + (size_t)U * 4;
            __builtin_amdgcn_global_load_lds((gas_ptr)(const void*)src, (las_ptr)(void*)dst, 16, 0, 0);
        }
    };

    auto COMPUTE = [&](int bidx, QF& qc) {
        const float* bp = lds + bidx * LDS_BUF_F;
        int rw = nfl * 16 + (l & 15);
        int cg = l >> 4;
        #pragma unroll
        for (int ks = 0; ks < 4; ++ks) {
            int g0 = ks * 8 + cg * 2;
            f32x4 x0 = *(const f32x4*)(bp + rw * KC + ((g0 ^ (rw & 7)) << 2));
            f32x4 x1 = *(const f32x4*)(bp + rw * KC + (((g0 + 1) ^ (rw & 7)) << 2));
            h16x8 hi, lo;
            float ps = 0.f;
            #pragma unroll
            for (int i2 = 0; i2 < 4; ++i2) {
                float v0 = x0[i2]; _Float16 h0 = (_Float16)v0;
                hi[i2] = h0; lo[i2] = (_Float16)((v0 - (float)h0) * 2048.0f);
                ps += v0 * v0;
                float v1 = x1[i2]; _Float16 h1 = (_Float16)v1;
                hi[4 + i2] = h1; lo[4 + i2] = (_Float16)((v1 - (float)h1) * 2048.0f);
                ps += v1 * v1;
            }
            if (qfp == 0) psum += ps;
            #pragma unroll
            for (int j = 0; j < 2; ++j) {
                accH[j] = __builtin_amdgcn_mfma_f32_16x16x32_f16(qc.h[j][ks], hi, accH[j], 0, 0, 0);
                accX[j] = __builtin_amdgcn_mfma_f32_16x16x32_f16(qc.h[j][ks], lo, accX[j], 0, 0, 0);
                accX[j] = __builtin_amdgcn_mfma_f32_16x16x32_f16(qc.l[j][ks], hi, accX[j], 0, 0, 0);
            }
        }
    };

    auto TAIL = [&](int tile) {
        // corpus row norms (owned by qfp==0 waves)
        float s = psum;
        s += __shfl_xor(s, 16);
        s += __shfl_xor(s, 32);
        if (qfp == 0 && l < 16) cnF[nfl * 16 + l] = sqrtf(s);
        asm volatile("s_waitcnt lgkmcnt(0)" ::: "memory");
        __builtin_amdgcn_s_barrier();
        // sim writes
        int n = nfl * 16 + (l & 15);
        float inv = 1.0f / cnF[n];
        #pragma unroll
        for (int j = 0; j < 2; ++j)
            #pragma unroll
            for (int r = 0; r < 4; ++r) {
                int q = qfp * 32 + j * 16 + (l >> 4) * 4 + r;
                float dot = accH[j][r] + accX[j][r] * (1.0f / 2048.0f);
                simF[q * SIMST + n] = dot * inv;
            }
        asm volatile("s_waitcnt lgkmcnt(0)" ::: "memory");
        __builtin_amdgcn_s_barrier();
        // per-query top-16 over this tile's 64 rows: 8 threads per query
        int q = t >> 3, sl = t & 7;
        float tv[16]; int ti[16];
        #pragma unroll
        for (int s2 = 0; s2 < 16; ++s2) { tv[s2] = -INFINITY; ti[s2] = 0x7fffffff; }
        #pragma unroll
        for (int i = 0; i < 8; ++i) {
            int n2 = sl * 8 + i;
            int g = tile * NT + n2;
            if (g < N) topk_insert(tv, ti, simF[q * SIMST + n2], g);
        }
        lane_merge(tv, ti, 1); lane_merge(tv, ti, 2); lane_merge(tv, ti, 4);
        if (sl == 0) {
            float2* dst = cand + ((size_t)q * NTILES + tile) * 16;
            #pragma unroll
            for (int s2 = 0; s2 < 16; ++s2) dst[s2] = make_float2(tv[s2], __int_as_float(ti[s2]));
        }
        // reset accumulators
        #pragma unroll
        for (int j = 0; j < 2; ++j) { accH[j] = (f32x4)(0.f); accX[j] = (f32x4)(0.f); }
        psum = 0.f;
    };

    auto BODY = [&](int cc, QF& qc, QF& qn) {
        int cm = cc % NCHT;
        if (cc + 1 < NC) QLOAD((cc + 1) % NCHT, qn);
        if (cc + 2 < NC) STAGE(cc + 2);
        // counted waits: ensure STAGE(cc) and Q(cc) complete, keep newer in flight.
        // issue counts: QLOAD=16, STAGE=4, tail cand-store=16 (after tile end)
        if (cc == 0) {
            asm volatile("s_waitcnt vmcnt(20)" ::: "memory");
        } else if (cc + 2 >= NC) {
            if (cc + 1 < NC) { asm volatile("s_waitcnt vmcnt(20)" ::: "memory"); }
            else             { asm volatile("s_waitcnt vmcnt(0)"  ::: "memory"); }
        } else if (cm == 0) {
            asm volatile("s_waitcnt vmcnt(40)" ::: "memory");   // +16 tail stores in window
        } else {
            asm volatile("s_waitcnt vmcnt(24)" ::: "memory");
        }
        __builtin_amdgcn_sched_barrier(0);
        __builtin_amdgcn_s_barrier();
        __builtin_amdgcn_sched_barrier(0);
        COMPUTE(cc & 3, qc);
        if (cm == NCHT - 1) TAIL(tstart + cc / NCHT);
    };

    // prologue: two chunks in flight + Q(0)
    STAGE(0); STAGE(1); QLOAD(0, qA);
    int half = NC >> 1;   // NC is even (cnt*6)
    for (int m = 0; m < half; ++m) {
        BODY(2 * m,     qA, qB);
        BODY(2 * m + 1, qB, qA);
    }
}

// ---------- kernel 2a: partial merge — 8 segments per query ----------
__global__ __launch_bounds__(256)
void merge1_kernel(const float2* __restrict__ cand, float2* __restrict__ cand2, int NTILES) {
    int q = blockIdx.x >> 3, seg = blockIdx.x & (NS - 1);
    int t = threadIdx.x, w = t >> 6, l = t & 63;
    int total = NTILES * 16;
    int chunk = (total + NS - 1) / NS;
    int e0 = seg * chunk, e1 = min(total, e0 + chunk);
    const float2* src = cand + (size_t)q * total;
    float tv[16]; int ti[16];
    #pragma unroll
    for (int s = 0; s < 16; ++s) { tv[s] = -INFINITY; ti[s] = 0x7fffffff; }
    for (int e = e0 + t; e < e1; e += 256) {
        float2 ce = src[e];
        topk_insert(tv, ti, ce.x, __float_as_int(ce.y));
    }
    lane_merge(tv, ti, 1);  lane_merge(tv, ti, 2);  lane_merge(tv, ti, 4);
    lane_merge(tv, ti, 8);  lane_merge(tv, ti, 16); lane_merge(tv, ti, 32);
    __shared__ float2 stage[64];
    if (l == 0) {
        #pragma unroll
        for (int s = 0; s < 16; ++s) stage[w * 16 + s] = make_float2(tv[s], __int_as_float(ti[s]));
    }
    __syncthreads();
    if (t < 64) {
        float2 ce = stage[t];
        float v = ce.x; int ix = __float_as_int(ce.y);
        sort64(v, ix, t);
        if (t < 16) cand2[((size_t)q * NS + seg) * 16 + t] = make_float2(v, __int_as_float(ix));
    }
}

// ---------- kernel 2b: final merge of 8x16=128 candidates per query ----------
__global__ __launch_bounds__(64)
void merge2_kernel(const float2* __restrict__ cand2, float* __restrict__ out) {
    int q = blockIdx.x, l = threadIdx.x;
    const float2* src = cand2 + (size_t)q * (NS * 16);
    float2 a = src[l], b = src[l + 64];
    float v1 = a.x; int i1 = __float_as_int(a.y);
    float v2 = b.x; int i2 = __float_as_int(b.y);
    sort64(v1, i1, l);
    sort64(v2, i2, l);
    float sv = __shfl(v2, (l - 16) & 63);
    int   si = __shfl(i2, (l - 16) & 63);
    float mv = (l < 16) ? v1 : ((l < 32) ? sv : -INFINITY);
    int   mi = (l < 16) ? i1 : ((l < 32) ? si : 0x7fffffff);
    sort64(mv, mi, l);
    if (l < 16) {
        out[q * 16 + l]           = mv;
        out[NQ * 16 + q * 16 + l] = (float)mi;
    }
}

extern "C" void kernel_launch(void* const* d_in, const int* in_sizes, int n_in,
                              void* d_out, int out_size, void* d_ws, size_t ws_size,
                              hipStream_t stream) {
    const float* query  = (const float*)d_in[0];
    const float* corpus = (const float*)d_in[1];
    int N      = in_sizes[1] / D;                 // 500000
    int NTILES = (N + NT - 1) / NT;               // 7813
    char* ws = (char*)d_ws;
    _Float16* qfh = (_Float16*)ws;                               // 98304 B
    _Float16* qfl = (_Float16*)(ws + 98304);                     // 98304 B
    float2*  cand = (float2*)(ws + 196608);                      // 64*NTILES*16*8 B (~64 MB)
    size_t candBytes = (size_t)NQ * NTILES * 16 * sizeof(float2);
    float2* cand2 = (float2*)(ws + 196608 + candBytes);
    float*   out  = (float*)d_out;

    // allow >64KB dynamic LDS (148 KB; gfx950 workgroup max is 160 KB)
    (void)hipFuncSetAttribute((const void*)sim_topk_kernel,
                              hipFuncAttributeMaxDynamicSharedMemorySize, LDS_BYTES);

    prep_kernel<<<NQ, 256, 0, stream>>>(query, qfh, qfl);
    sim_topk_kernel<<<GRID, TPB, LDS_BYTES, stream>>>(corpus, qfh, qfl, cand, N, NTILES);
    merge1_kernel<<<NQ * NS, 256, 0, stream>>>(cand, cand2, NTILES);
    merge2_kernel<<<NQ, 64, 0, stream>>>(cand2, out);
}

// Round 4
// 641.052 us; speedup vs baseline: 1.1741x; 1.1741x over previous
//
#include <hip/hip_runtime.h>
#include <hip/hip_bf16.h>

#define D 768
#define NQ 64
#define NT 128          // corpus rows per tile
#define KC 64           // fp32 cols per chunk
#define NCHT 12         // chunks per tile (768/64)
#define TPB 512
#define SIMST 133
#define NS 8            // merge1 segments per query

#define HST 72                       // padded halves per row (64 + 8)
#define BUF_HALVES (NT * HST)        // 9216 halves = 18KB per plane
#define BUF_STRIDE (2 * BUF_HALVES)  // hi+lo planes per buffer
#define LDS_CN_BYTE (2 * BUF_STRIDE * 2)   // 73728: cn floats after buffers
#define LDS_BYTES (LDS_CN_BYTE + NT * 4)   // 74240 B

typedef float    f32x4 __attribute__((ext_vector_type(4)));
typedef _Float16 h16x8 __attribute__((ext_vector_type(8)));
typedef _Float16 h16x4 __attribute__((ext_vector_type(4)));

// ---------- top-k helpers (static-indexed: stays in VGPRs) ----------
__device__ __forceinline__ bool kbetter(float v1, int i1, float v2, int i2) {
    return (v1 > v2) || (v1 == v2 && i1 < i2);
}

__device__ __forceinline__ void topk_insert(float (&tv)[16], int (&ti)[16], float v, int idx) {
    if (!kbetter(v, idx, tv[15], ti[15])) return;
    tv[15] = v; ti[15] = idx;
    #pragma unroll
    for (int s = 15; s >= 1; --s) {
        bool sw = kbetter(tv[s], ti[s], tv[s-1], ti[s-1]);
        float av = sw ? tv[s] : tv[s-1];
        float bv = sw ? tv[s-1] : tv[s];
        int   ai = sw ? ti[s] : ti[s-1];
        int   bi = sw ? ti[s-1] : ti[s];
        tv[s-1] = av; tv[s] = bv; ti[s-1] = ai; ti[s] = bi;
    }
}

__device__ __forceinline__ void bitonic16(float (&v)[16], int (&ix)[16]) {
    #pragma unroll
    for (int d = 8; d >= 1; d >>= 1) {
        #pragma unroll
        for (int i = 0; i < 16; ++i) {
            if ((i & d) == 0) {
                int j = i | d;
                bool sw = kbetter(v[j], ix[j], v[i], ix[i]);
                float av = sw ? v[j] : v[i];
                float bv = sw ? v[i] : v[j];
                int   ai = sw ? ix[j] : ix[i];
                int   bi = sw ? ix[i] : ix[j];
                v[i] = av; v[j] = bv; ix[i] = ai; ix[j] = bi;
            }
        }
    }
}

__device__ __forceinline__ void lane_merge(float (&v)[16], int (&ix)[16], int mask) {
    float pv[16]; int pix[16];
    #pragma unroll
    for (int i = 0; i < 16; ++i) {
        pv[i]  = __shfl_xor(v[15 - i], mask);
        pix[i] = __shfl_xor(ix[15 - i], mask);
    }
    #pragma unroll
    for (int i = 0; i < 16; ++i) {
        if (kbetter(pv[i], pix[i], v[i], ix[i])) { v[i] = pv[i]; ix[i] = pix[i]; }
    }
    bitonic16(v, ix);
}

__device__ __forceinline__ void sort64(float& v, int& ix, int l) {
    #pragma unroll
    for (int k = 2; k <= 64; k <<= 1) {
        #pragma unroll
        for (int j = k >> 1; j >= 1; j >>= 1) {
            float ov = __shfl_xor(v, j);
            int   oi = __shfl_xor(ix, j);
            bool dirDesc = ((l & k) == 0);
            bool lower   = ((l & j) == 0);
            bool takeBetter = (lower == dirDesc);
            bool ob = kbetter(ov, oi, v, ix);
            if (takeBetter == ob) { v = ov; ix = oi; }
        }
    }
}

// ---------- kernel 0: normalize Q rows, fp16 hi/lo split in MFMA-fragment order ----------
// layout: [cc(12)][kk(2)][qf(4)][lane(64)][8 halves]   (identical to R2 - verified absmax 0)
__global__ __launch_bounds__(256)
void prep_kernel(const float* __restrict__ query, _Float16* __restrict__ qfh,
                 _Float16* __restrict__ qfl) {
    int b = blockIdx.x, t = threadIdx.x;
    const float* row = query + b * D;
    float vals[3]; float s = 0.f;
    #pragma unroll
    for (int j = 0; j < 3; ++j) { vals[j] = row[t + 256 * j]; s += vals[j] * vals[j]; }
    #pragma unroll
    for (int m = 1; m < 64; m <<= 1) s += __shfl_xor(s, m);
    __shared__ float ws4[4];
    if ((t & 63) == 0) ws4[t >> 6] = s;
    __syncthreads();
    float qn = sqrtf(ws4[0] + ws4[1] + ws4[2] + ws4[3]);
    int qf = b >> 4;
    #pragma unroll
    for (int j = 0; j < 3; ++j) {
        int col = t + 256 * j;
        float vn = vals[j] / qn;
        _Float16 h = (_Float16)vn;
        float r = vn - (float)h;
        _Float16 l2 = (_Float16)(r * 2048.0f);
        int cc = col >> 6, kk = (col >> 5) & 1, unit = (col >> 3) & 3, sub = col & 7;
        int lane = (b & 15) + unit * 16;
        size_t off = ((((size_t)cc * 2 + kk) * 4 + qf) * 64 + lane) * 8 + sub;
        qfh[off] = h;
        qfl[off] = l2;
    }
}

// ---------- kernel 1: reg-staged async split + fp16-in-LDS MFMA + per-tile top-16 ----------
__global__ __launch_bounds__(TPB, 4)
void sim_topk_kernel(const float* __restrict__ corpus,
                     const _Float16* __restrict__ qfh,
                     const _Float16* __restrict__ qfl,
                     float2* __restrict__ cand,   // [NQ][NTILES][16]
                     int N, int NTILES) {
    extern __shared__ __align__(16) char smem[];
    _Float16* bufs = (_Float16*)smem;
    float*    cnF  = (float*)(smem + LDS_CN_BYTE);
    float*    simF = (float*)smem;          // overlays buffers at tail

    int t = threadIdx.x, w = t >> 6, l = t & 63;
    int b = blockIdx.x;
    long n0 = (long)b * NT;

    f32x4 accH[4], accX[4];
    #pragma unroll
    for (int qf = 0; qf < 4; ++qf) { accH[qf] = (f32x4)(0.f); accX[qf] = (f32x4)(0.f); }
    float psum[4] = {0.f, 0.f, 0.f, 0.f};

    int rw = w * 16 + (l & 15);   // this lane's corpus row within tile
    int cg = l >> 4;

    // load chunk c of this tile into regs (4 x float4 per thread)
    auto LOADSTG = [&](int c, float4 (&stg)[4]) {
        #pragma unroll
        for (int jj = 0; jj < 4; ++jj) {
            int U = t + TPB * jj;
            int r = U >> 4, u = U & 15;
            long grow = n0 + r; if (grow > N - 1) grow = N - 1;
            stg[jj] = *(const float4*)(corpus + (size_t)grow * D + c * KC + u * 4);
        }
    };

    // convert staged regs -> fp16 hi/lo planes of buffer `buf`, accumulate psum
    auto CONV = [&](float4 (&stg)[4], int buf) {
        _Float16* bh = bufs + buf * BUF_STRIDE;
        _Float16* blo = bh + BUF_HALVES;
        #pragma unroll
        for (int jj = 0; jj < 4; ++jj) {
            int U = t + TPB * jj;
            int r = U >> 4, u = U & 15;
            float4 x = stg[jj];
            psum[jj] += x.x * x.x + x.y * x.y + x.z * x.z + x.w * x.w;
            h16x4 h, lo;
            h.x = (_Float16)x.x; h.y = (_Float16)x.y; h.z = (_Float16)x.z; h.w = (_Float16)x.w;
            lo.x = (_Float16)((x.x - (float)h.x) * 2048.0f);
            lo.y = (_Float16)((x.y - (float)h.y) * 2048.0f);
            lo.z = (_Float16)((x.z - (float)h.z) * 2048.0f);
            lo.w = (_Float16)((x.w - (float)h.w) * 2048.0f);
            *(h16x4*)(bh  + r * HST + u * 4) = h;
            *(h16x4*)(blo + r * HST + u * 4) = lo;
        }
    };

    // prologue: stage chunk 0 into buf 0
    {
        float4 stg[4];
        LOADSTG(0, stg);
        CONV(stg, 0);
    }
    __syncthreads();

    for (int c = 0; c < NCHT; ++c) {
        // 1) Q fragments for chunk c — issued FIRST so their waits keep the
        //    corpus prefetch (issued below) in flight (vmcnt retires in order)
        h16x8 qh[2][4], ql[2][4];
        #pragma unroll
        for (int kk = 0; kk < 2; ++kk)
            #pragma unroll
            for (int qf = 0; qf < 4; ++qf) {
                size_t qoff = ((((size_t)c * 2 + kk) * 4 + qf) * 64 + l) * 8;
                qh[kk][qf] = *(const h16x8*)(qfh + qoff);
                ql[kk][qf] = *(const h16x8*)(qfl + qoff);
            }
        // 2) corpus prefetch for chunk c+1 -> regs (in flight during compute)
        float4 stg[4];
        if (c + 1 < NCHT) LOADSTG(c + 1, stg);
        // 3) compute chunk c from LDS fp16 tiles
        const _Float16* bh = bufs + (c & 1) * BUF_STRIDE;
        const _Float16* blo = bh + BUF_HALVES;
        #pragma unroll
        for (int kk = 0; kk < 2; ++kk) {
            h16x8 ch = *(const h16x8*)(bh  + rw * HST + kk * 32 + cg * 8);
            h16x8 cl = *(const h16x8*)(blo + rw * HST + kk * 32 + cg * 8);
            #pragma unroll
            for (int qf = 0; qf < 4; ++qf) {
                accH[qf] = __builtin_amdgcn_mfma_f32_16x16x32_f16(qh[kk][qf], ch, accH[qf], 0, 0, 0);
                accX[qf] = __builtin_amdgcn_mfma_f32_16x16x32_f16(qh[kk][qf], cl, accX[qf], 0, 0, 0);
                accX[qf] = __builtin_amdgcn_mfma_f32_16x16x32_f16(ql[kk][qf], ch, accX[qf], 0, 0, 0);
            }
        }
        // 4) convert staged c+1 into the other buffer (vmcnt wait hidden under compute)
        if (c + 1 < NCHT) CONV(stg, (c + 1) & 1);
        // 5) barrier waits only LDS writes — never HBM
        __syncthreads();
    }

    // ---- tail ----
    // corpus row norms: reduce psum[jj] (row (t>>4)+32*jj) over 16 col-slice threads
    #pragma unroll
    for (int jj = 0; jj < 4; ++jj) {
        float s = psum[jj];
        s += __shfl_xor(s, 1); s += __shfl_xor(s, 2);
        s += __shfl_xor(s, 4); s += __shfl_xor(s, 8);
        if ((t & 15) == 0) cnF[(t >> 4) + 32 * jj] = sqrtf(s);
    }
    __syncthreads();
    float inv = 1.0f / cnF[rw];
    __syncthreads();   // cn read before sim overlay clobbers buffers
    #pragma unroll
    for (int qf = 0; qf < 4; ++qf)
        #pragma unroll
        for (int r = 0; r < 4; ++r) {
            int q = qf * 16 + cg * 4 + r;
            float dot = accH[qf][r] + accX[qf][r] * (1.0f / 2048.0f);
            simF[q * SIMST + rw] = dot * inv;
        }
    __syncthreads();

    // per-query top-16 over the tile's 128 rows: 8 threads per query
    int q = t >> 3, sl = t & 7;
    float tv[16]; int ti[16];
    #pragma unroll
    for (int s2 = 0; s2 < 16; ++s2) { tv[s2] = -INFINITY; ti[s2] = 0x7fffffff; }
    #pragma unroll
    for (int i = 0; i < 16; ++i) {
        int n = sl * 16 + i;
        long g = n0 + n;
        if (g < N) topk_insert(tv, ti, simF[q * SIMST + n], (int)g);
    }
    lane_merge(tv, ti, 1); lane_merge(tv, ti, 2); lane_merge(tv, ti, 4);
    if (sl == 0) {
        float2* dst = cand + ((size_t)q * NTILES + b) * 16;
        #pragma unroll
        for (int s2 = 0; s2 < 16; ++s2) dst[s2] = make_float2(tv[s2], __int_as_float(ti[s2]));
    }
}

// ---------- kernel 2a: partial merge — 8 segments per query ----------
__global__ __launch_bounds__(256)
void merge1_kernel(const float2* __restrict__ cand, float2* __restrict__ cand2, int NTILES) {
    int q = blockIdx.x >> 3, seg = blockIdx.x & (NS - 1);
    int t = threadIdx.x, w = t >> 6, l = t & 63;
    int total = NTILES * 16;
    int chunk = (total + NS - 1) / NS;
    int e0 = seg * chunk, e1 = min(total, e0 + chunk);
    const float2* src = cand + (size_t)q * total;
    float tv[16]; int ti[16];
    #pragma unroll
    for (int s = 0; s < 16; ++s) { tv[s] = -INFINITY; ti[s] = 0x7fffffff; }
    for (int e = e0 + t; e < e1; e += 256) {
        float2 ce = src[e];
        topk_insert(tv, ti, ce.x, __float_as_int(ce.y));
    }
    lane_merge(tv, ti, 1);  lane_merge(tv, ti, 2);  lane_merge(tv, ti, 4);
    lane_merge(tv, ti, 8);  lane_merge(tv, ti, 16); lane_merge(tv, ti, 32);
    __shared__ float2 stage[64];
    if (l == 0) {
        #pragma unroll
        for (int s = 0; s < 16; ++s) stage[w * 16 + s] = make_float2(tv[s], __int_as_float(ti[s]));
    }
    __syncthreads();
    if (t < 64) {
        float2 ce = stage[t];
        float v = ce.x; int ix = __float_as_int(ce.y);
        sort64(v, ix, t);
        if (t < 16) cand2[((size_t)q * NS + seg) * 16 + t] = make_float2(v, __int_as_float(ix));
    }
}

// ---------- kernel 2b: final merge of 8x16=128 candidates per query ----------
__global__ __launch_bounds__(64)
void merge2_kernel(const float2* __restrict__ cand2, float* __restrict__ out) {
    int q = blockIdx.x, l = threadIdx.x;
    const float2* src = cand2 + (size_t)q * (NS * 16);
    float2 a = src[l], b = src[l + 64];
    float v1 = a.x; int i1 = __float_as_int(a.y);
    float v2 = b.x; int i2 = __float_as_int(b.y);
    sort64(v1, i1, l);
    sort64(v2, i2, l);
    float sv = __shfl(v2, (l - 16) & 63);
    int   si = __shfl(i2, (l - 16) & 63);
    float mv = (l < 16) ? v1 : ((l < 32) ? sv : -INFINITY);
    int   mi = (l < 16) ? i1 : ((l < 32) ? si : 0x7fffffff);
    sort64(mv, mi, l);
    if (l < 16) {
        out[q * 16 + l]           = mv;
        out[NQ * 16 + q * 16 + l] = (float)mi;
    }
}

extern "C" void kernel_launch(void* const* d_in, const int* in_sizes, int n_in,
                              void* d_out, int out_size, void* d_ws, size_t ws_size,
                              hipStream_t stream) {
    const float* query  = (const float*)d_in[0];
    const float* corpus = (const float*)d_in[1];
    int N      = in_sizes[1] / D;                 // 500000
    int NTILES = (N + NT - 1) / NT;               // 3907
    char* ws = (char*)d_ws;
    _Float16* qfh = (_Float16*)ws;                               // 98304 B
    _Float16* qfl = (_Float16*)(ws + 98304);                     // 98304 B
    float2*  cand = (float2*)(ws + 196608);                      // 64*NTILES*16*8 B (~32 MB)
    size_t candBytes = (size_t)NQ * NTILES * 16 * sizeof(float2);
    float2* cand2 = (float2*)(ws + 196608 + candBytes);          // 64KB
    float*   out  = (float*)d_out;

    (void)hipFuncSetAttribute((const void*)sim_topk_kernel,
                              hipFuncAttributeMaxDynamicSharedMemorySize, LDS_BYTES);

    prep_kernel<<<NQ, 256, 0, stream>>>(query, qfh, qfl);
    sim_topk_kernel<<<NTILES, TPB, LDS_BYTES, stream>>>(corpus, qfh, qfl, cand, N, NTILES);
    merge1_kernel<<<NQ * NS, 256, 0, stream>>>(cand, cand2, NTILES);
    merge2_kernel<<<NQ, 64, 0, stream>>>(cand2, out);
}

// Round 5
// 614.158 us; speedup vs baseline: 1.2255x; 1.0438x over previous
//
#include <hip/hip_runtime.h>
#include <hip/hip_bf16.h>

#define D 768
#define NQ 64
#define TPB 256
#define GRID 1303
#define NWAVES (GRID * 4)     // 5212
#define KSTEPS 24             // 768 / 32
#define SIMP 20               // padded floats per query row in transpose scratch
#define NS 8                  // merge1 segments per query

typedef float    f32x4 __attribute__((ext_vector_type(4)));
typedef _Float16 h16x8 __attribute__((ext_vector_type(8)));

// ---------- top-k helpers (static-indexed: stays in VGPRs) ----------
__device__ __forceinline__ bool kbetter(float v1, int i1, float v2, int i2) {
    return (v1 > v2) || (v1 == v2 && i1 < i2);
}

__device__ __forceinline__ void topk_insert(float (&tv)[16], int (&ti)[16], float v, int idx) {
    if (!kbetter(v, idx, tv[15], ti[15])) return;
    tv[15] = v; ti[15] = idx;
    #pragma unroll
    for (int s = 15; s >= 1; --s) {
        bool sw = kbetter(tv[s], ti[s], tv[s-1], ti[s-1]);
        float av = sw ? tv[s] : tv[s-1];
        float bv = sw ? tv[s-1] : tv[s];
        int   ai = sw ? ti[s] : ti[s-1];
        int   bi = sw ? ti[s-1] : ti[s];
        tv[s-1] = av; tv[s] = bv; ti[s-1] = ai; ti[s] = bi;
    }
}

__device__ __forceinline__ void bitonic16(float (&v)[16], int (&ix)[16]) {
    #pragma unroll
    for (int d = 8; d >= 1; d >>= 1) {
        #pragma unroll
        for (int i = 0; i < 16; ++i) {
            if ((i & d) == 0) {
                int j = i | d;
                bool sw = kbetter(v[j], ix[j], v[i], ix[i]);
                float av = sw ? v[j] : v[i];
                float bv = sw ? v[i] : v[j];
                int   ai = sw ? ix[j] : ix[i];
                int   bi = sw ? ix[i] : ix[j];
                v[i] = av; v[j] = bv; ix[i] = ai; ix[j] = bi;
            }
        }
    }
}

__device__ __forceinline__ void lane_merge(float (&v)[16], int (&ix)[16], int mask) {
    float pv[16]; int pix[16];
    #pragma unroll
    for (int i = 0; i < 16; ++i) {
        pv[i]  = __shfl_xor(v[15 - i], mask);
        pix[i] = __shfl_xor(ix[15 - i], mask);
    }
    #pragma unroll
    for (int i = 0; i < 16; ++i) {
        if (kbetter(pv[i], pix[i], v[i], ix[i])) { v[i] = pv[i]; ix[i] = pix[i]; }
    }
    bitonic16(v, ix);
}

__device__ __forceinline__ void sort64(float& v, int& ix, int l) {
    #pragma unroll
    for (int k = 2; k <= 64; k <<= 1) {
        #pragma unroll
        for (int j = k >> 1; j >= 1; j >>= 1) {
            float ov = __shfl_xor(v, j);
            int   oi = __shfl_xor(ix, j);
            bool dirDesc = ((l & k) == 0);
            bool lower   = ((l & j) == 0);
            bool takeBetter = (lower == dirDesc);
            bool ob = kbetter(ov, oi, v, ix);
            if (takeBetter == ob) { v = ov; ix = oi; }
        }
    }
}

// ---------- kernel 0: normalize Q rows, fp16 hi/lo split, packed fragment order ----------
// layout: [ks(24)][qf(4)][lane(64)][hi 8 | lo 8] halves  (32 B per lane-fragment)
__global__ __launch_bounds__(256)
void prep_kernel(const float* __restrict__ query, _Float16* __restrict__ qpk) {
    int b = blockIdx.x, t = threadIdx.x;
    const float* row = query + b * D;
    float vals[3]; float s = 0.f;
    #pragma unroll
    for (int j = 0; j < 3; ++j) { vals[j] = row[t + 256 * j]; s += vals[j] * vals[j]; }
    #pragma unroll
    for (int m = 1; m < 64; m <<= 1) s += __shfl_xor(s, m);
    __shared__ float ws4[4];
    if ((t & 63) == 0) ws4[t >> 6] = s;
    __syncthreads();
    float qn = sqrtf(ws4[0] + ws4[1] + ws4[2] + ws4[3]);
    int qf = b >> 4;
    #pragma unroll
    for (int j = 0; j < 3; ++j) {
        int col = t + 256 * j;
        float vn = vals[j] / qn;
        _Float16 h = (_Float16)vn;
        float r = vn - (float)h;
        _Float16 l2 = (_Float16)(r * 2048.0f);
        int ks = col >> 5, unit = (col >> 3) & 3, sub = col & 7;
        int lane = (b & 15) + unit * 16;
        size_t off = (((size_t)ks * 4 + qf) * 64 + lane) * 16 + sub;
        qpk[off]     = h;
        qpk[off + 8] = l2;
    }
}

// ---------- kernel 1: barrier-free direct-from-global MFMA + register top-16 ----------
// Each wave owns 32 corpus rows per group iteration and ALL 64 queries.
// Lane l permanently owns query l's running top-16.
__global__ __launch_bounds__(TPB, 2)
void sim_topk_kernel(const float* __restrict__ corpus,
                     const _Float16* __restrict__ qpk,
                     float2* __restrict__ cand,   // [NQ][NWAVES][16]
                     int N, int NG) {
    __shared__ float scratch[4][NQ * SIMP];   // per-wave private transpose tile
    int t = threadIdx.x, w = t >> 6, l = t & 63;
    int ww = blockIdx.x * 4 + w;
    int n16 = l & 15, kg = l >> 4;
    float* sc = scratch[w];

    float tv[16]; int ti[16];
    #pragma unroll
    for (int s = 0; s < 16; ++s) { tv[s] = -INFINITY; ti[s] = 0x7fffffff; }

    for (int g = ww; g < NG; g += NWAVES) {
        long baseA = (long)g * 32;
        long rA = baseA + n16;      if (rA > N - 1) rA = N - 1;
        long rB = baseA + 16 + n16; if (rB > N - 1) rB = N - 1;
        const float* pA = corpus + (size_t)rA * D + kg * 8;
        const float* pB = corpus + (size_t)rB * D + kg * 8;

        f32x4 accAH[4], accAX[4], accBH[4], accBX[4];
        #pragma unroll
        for (int qf = 0; qf < 4; ++qf) {
            accAH[qf] = (f32x4)(0.f); accAX[qf] = (f32x4)(0.f);
            accBH[qf] = (f32x4)(0.f); accBX[qf] = (f32x4)(0.f);
        }
        float psA = 0.f, psB = 0.f;

        #pragma unroll 2
        for (int ks = 0; ks < KSTEPS; ++ks) {
            // Q fragments (hi|lo packed, contiguous 2KB per (ks,qf) across the wave; L2-hot)
            h16x8 qh[4], ql[4];
            #pragma unroll
            for (int qf = 0; qf < 4; ++qf) {
                const _Float16* qp = qpk + (((size_t)ks * 4 + qf) * 64 + l) * 16;
                qh[qf] = *(const h16x8*)qp;
                ql[qf] = *(const h16x8*)(qp + 8);
            }
            // corpus B-fragments: 8 floats per subgroup, straight from global
            f32x4 a0 = *(const f32x4*)(pA + ks * 32);
            f32x4 a1 = *(const f32x4*)(pA + ks * 32 + 4);
            f32x4 b0 = *(const f32x4*)(pB + ks * 32);
            f32x4 b1 = *(const f32x4*)(pB + ks * 32 + 4);

            h16x8 hiA, loA, hiB, loB;
            #pragma unroll
            for (int i = 0; i < 4; ++i) {
                float va = a0[i]; _Float16 ha = (_Float16)va;
                hiA[i] = ha; loA[i] = (_Float16)((va - (float)ha) * 2048.0f);
                psA += va * va;
                float va1 = a1[i]; _Float16 ha1 = (_Float16)va1;
                hiA[4 + i] = ha1; loA[4 + i] = (_Float16)((va1 - (float)ha1) * 2048.0f);
                psA += va1 * va1;
                float vb = b0[i]; _Float16 hb = (_Float16)vb;
                hiB[i] = hb; loB[i] = (_Float16)((vb - (float)hb) * 2048.0f);
                psB += vb * vb;
                float vb1 = b1[i]; _Float16 hb1 = (_Float16)vb1;
                hiB[4 + i] = hb1; loB[4 + i] = (_Float16)((vb1 - (float)hb1) * 2048.0f);
                psB += vb1 * vb1;
            }
            #pragma unroll
            for (int qf = 0; qf < 4; ++qf) {
                accAH[qf] = __builtin_amdgcn_mfma_f32_16x16x32_f16(qh[qf], hiA, accAH[qf], 0, 0, 0);
                accAX[qf] = __builtin_amdgcn_mfma_f32_16x16x32_f16(qh[qf], loA, accAX[qf], 0, 0, 0);
                accAX[qf] = __builtin_amdgcn_mfma_f32_16x16x32_f16(ql[qf], hiA, accAX[qf], 0, 0, 0);
                accBH[qf] = __builtin_amdgcn_mfma_f32_16x16x32_f16(qh[qf], hiB, accBH[qf], 0, 0, 0);
                accBX[qf] = __builtin_amdgcn_mfma_f32_16x16x32_f16(qh[qf], loB, accBX[qf], 0, 0, 0);
                accBX[qf] = __builtin_amdgcn_mfma_f32_16x16x32_f16(ql[qf], hiB, accBX[qf], 0, 0, 0);
            }
        }

        // corpus row norms: lanes {l, l^16, l^32, l^48} hold k-slices of the same row
        psA += __shfl_xor(psA, 16); psA += __shfl_xor(psA, 32);
        psB += __shfl_xor(psB, 16); psB += __shfl_xor(psB, 32);
        float invA = 1.0f / sqrtf(psA);
        float invB = 1.0f / sqrtf(psB);

        // subgroup A: per-wave LDS transpose (no barrier; lgkmcnt orders within wave)
        #pragma unroll
        for (int qf = 0; qf < 4; ++qf)
            #pragma unroll
            for (int r = 0; r < 4; ++r) {
                int q = qf * 16 + kg * 4 + r;
                sc[q * SIMP + n16] = (accAH[qf][r] + accAX[qf][r] * (1.0f / 2048.0f)) * invA;
            }
        {
            f32x4 sv[4];
            #pragma unroll
            for (int j = 0; j < 4; ++j) sv[j] = *(const f32x4*)(sc + l * SIMP + j * 4);
            #pragma unroll
            for (int j = 0; j < 4; ++j)
                #pragma unroll
                for (int e = 0; e < 4; ++e) {
                    long gidx = baseA + j * 4 + e;
                    if (gidx < N) topk_insert(tv, ti, sv[j][e], (int)gidx);
                }
        }
        // subgroup B
        #pragma unroll
        for (int qf = 0; qf < 4; ++qf)
            #pragma unroll
            for (int r = 0; r < 4; ++r) {
                int q = qf * 16 + kg * 4 + r;
                sc[q * SIMP + n16] = (accBH[qf][r] + accBX[qf][r] * (1.0f / 2048.0f)) * invB;
            }
        {
            f32x4 sv[4];
            #pragma unroll
            for (int j = 0; j < 4; ++j) sv[j] = *(const f32x4*)(sc + l * SIMP + j * 4);
            #pragma unroll
            for (int j = 0; j < 4; ++j)
                #pragma unroll
                for (int e = 0; e < 4; ++e) {
                    long gidx = baseA + 16 + j * 4 + e;
                    if (gidx < N) topk_insert(tv, ti, sv[j][e], (int)gidx);
                }
        }
    }

    // lane l owns query l: emit its top-16
    float2* dst = cand + ((size_t)l * NWAVES + ww) * 16;
    #pragma unroll
    for (int s = 0; s < 16; ++s) dst[s] = make_float2(tv[s], __int_as_float(ti[s]));
}

// ---------- kernel 2a: partial merge — 8 segments per query ----------
__global__ __launch_bounds__(256)
void merge1_kernel(const float2* __restrict__ cand, float2* __restrict__ cand2, int NWV) {
    int q = blockIdx.x >> 3, seg = blockIdx.x & (NS - 1);
    int t = threadIdx.x, w = t >> 6, l = t & 63;
    int total = NWV * 16;
    int chunk = (total + NS - 1) / NS;
    int e0 = seg * chunk, e1 = min(total, e0 + chunk);
    const float2* src = cand + (size_t)q * total;
    float tv[16]; int ti[16];
    #pragma unroll
    for (int s = 0; s < 16; ++s) { tv[s] = -INFINITY; ti[s] = 0x7fffffff; }
    for (int e = e0 + t; e < e1; e += 256) {
        float2 ce = src[e];
        topk_insert(tv, ti, ce.x, __float_as_int(ce.y));
    }
    lane_merge(tv, ti, 1);  lane_merge(tv, ti, 2);  lane_merge(tv, ti, 4);
    lane_merge(tv, ti, 8);  lane_merge(tv, ti, 16); lane_merge(tv, ti, 32);
    __shared__ float2 stage[64];
    if (l == 0) {
        #pragma unroll
        for (int s = 0; s < 16; ++s) stage[w * 16 + s] = make_float2(tv[s], __int_as_float(ti[s]));
    }
    __syncthreads();
    if (t < 64) {
        float2 ce = stage[t];
        float v = ce.x; int ix = __float_as_int(ce.y);
        sort64(v, ix, t);
        if (t < 16) cand2[((size_t)q * NS + seg) * 16 + t] = make_float2(v, __int_as_float(ix));
    }
}

// ---------- kernel 2b: final merge of 8x16=128 candidates per query ----------
__global__ __launch_bounds__(64)
void merge2_kernel(const float2* __restrict__ cand2, float* __restrict__ out) {
    int q = blockIdx.x, l = threadIdx.x;
    const float2* src = cand2 + (size_t)q * (NS * 16);
    float2 a = src[l], b = src[l + 64];
    float v1 = a.x; int i1 = __float_as_int(a.y);
    float v2 = b.x; int i2 = __float_as_int(b.y);
    sort64(v1, i1, l);
    sort64(v2, i2, l);
    float sv = __shfl(v2, (l - 16) & 63);
    int   si = __shfl(i2, (l - 16) & 63);
    float mv = (l < 16) ? v1 : ((l < 32) ? sv : -INFINITY);
    int   mi = (l < 16) ? i1 : ((l < 32) ? si : 0x7fffffff);
    sort64(mv, mi, l);
    if (l < 16) {
        out[q * 16 + l]           = mv;
        out[NQ * 16 + q * 16 + l] = (float)mi;
    }
}

extern "C" void kernel_launch(void* const* d_in, const int* in_sizes, int n_in,
                              void* d_out, int out_size, void* d_ws, size_t ws_size,
                              hipStream_t stream) {
    const float* query  = (const float*)d_in[0];
    const float* corpus = (const float*)d_in[1];
    int N  = in_sizes[1] / D;                 // 500000
    int NG = (N + 31) / 32;                   // 15625 row-groups of 32
    char* ws = (char*)d_ws;
    _Float16* qpk = (_Float16*)ws;                              // 196608 B
    float2*  cand = (float2*)(ws + 196608);                     // 64*NWAVES*16*8 B (~43 MB)
    size_t candBytes = (size_t)NQ * NWAVES * 16 * sizeof(float2);
    float2* cand2 = (float2*)(ws + 196608 + candBytes);         // 64KB
    float*   out  = (float*)d_out;

    prep_kernel<<<NQ, 256, 0, stream>>>(query, qpk);
    sim_topk_kernel<<<GRID, TPB, 0, stream>>>(corpus, qpk, cand, N, NG);
    merge1_kernel<<<NQ * NS, 256, 0, stream>>>(cand, cand2, NWAVES);
    merge2_kernel<<<NQ, 64, 0, stream>>>(cand2, out);
}